// Round 4
// baseline (305.413 us; speedup 1.0000x reference)
//
#include <hip/hip_runtime.h>
#include <stdint.h>

// ---------------------------------------------------------------------------
// kWTA: threshold = K-th largest of N fp32; out[i] = in[i] < thr ? 0 : in[i]
//
// Key structural idea: winners are tiny (K=1024 of 33.5M). Never write a
// dense output from a compute kernel:
//   - hipMemsetAsync zeroes the whole output at fill rate (~6.8 TB/s)
//   - K1: 4096-bin LDS histogram of top-12 key bits AND optimistic candidate
//         gather (all elements >= 3.5) in the same single read pass
//   - K2: suffix-scan -> bucket of the K-th element + rank within bucket;
//         validates the optimistic filter (bucket >= bin(3.5) => candidate
//         list provably complete). If invalid: zero list, flag fallback.
//   - K3: fallback gather (bins >= sel), skipped (early-exit) when filter ok
//   - K4: single-block 4-bit radix select over candidates -> exact threshold;
//         scatter-write ALL winners (key >= thr) into the zeroed output
// Exact for arbitrary inputs via the fallback path.
//
// (Round-2 lesson kept: NO in-kernel grid fusion / device-scope fences —
// dispatch boundaries provide visibility for free on MI355X.)
// ---------------------------------------------------------------------------

#define HIST_BINS 4096
#define CTRL_OFF  HIST_BINS        // word offset of control block in ws
#define CAND_OFF  (HIST_BINS + 16) // word offset of candidate buffers
// ctrl[0] = candidate counter, ctrl[1] = selected bucket,
// ctrl[2] = rank within bucket (1-based, from top), ctrl[3] = threshold bits,
// ctrl[6] = need-fallback-gather flag

// f2key(3.5f) = 0xC0600000 (low 20 bits zero -> bin compare == key compare)
#define FILTER_KEY 0xC0600000u

typedef float f32x4 __attribute__((ext_vector_type(4)));

__device__ __forceinline__ uint32_t f2key(float x) {
  uint32_t u = __float_as_uint(x);
  return (u & 0x80000000u) ? ~u : (u | 0x80000000u);  // larger key <=> larger float
}
__device__ __forceinline__ float key2f(uint32_t k) {
  uint32_t u = (k & 0x80000000u) ? (k & 0x7fffffffu) : ~k;
  return __uint_as_float(u);
}

// K1: histogram + optimistic candidate gather, one read pass
__global__ void k_hist_filter(const float4* __restrict__ in, int n4, int ntail,
                              const float* __restrict__ in_s,
                              uint32_t* __restrict__ ghist,
                              uint32_t* __restrict__ ctrl,
                              uint32_t* __restrict__ keys,
                              uint32_t* __restrict__ idxs, uint32_t cap) {
  __shared__ uint32_t lh[HIST_BINS];
  for (int i = threadIdx.x; i < HIST_BINS; i += blockDim.x) lh[i] = 0;
  __syncthreads();
  int stride = gridDim.x * blockDim.x;
  for (int i = blockIdx.x * blockDim.x + threadIdx.x; i < n4; i += stride) {
    f32x4 v = __builtin_nontemporal_load((const f32x4*)&in[i]);
    uint32_t k0 = f2key(v.x), k1 = f2key(v.y), k2 = f2key(v.z), k3 = f2key(v.w);
    atomicAdd(&lh[k0 >> 20], 1u);
    atomicAdd(&lh[k1 >> 20], 1u);
    atomicAdd(&lh[k2 >> 20], 1u);
    atomicAdd(&lh[k3 >> 20], 1u);
    // optimistic filter: ~2e-4 of Gaussian data passes -> trivial atomic rate
    if (k0 >= FILTER_KEY) { uint32_t p = atomicAdd(&ctrl[0], 1u); if (p < cap) { keys[p] = k0; idxs[p] = 4u * i + 0u; } }
    if (k1 >= FILTER_KEY) { uint32_t p = atomicAdd(&ctrl[0], 1u); if (p < cap) { keys[p] = k1; idxs[p] = 4u * i + 1u; } }
    if (k2 >= FILTER_KEY) { uint32_t p = atomicAdd(&ctrl[0], 1u); if (p < cap) { keys[p] = k2; idxs[p] = 4u * i + 2u; } }
    if (k3 >= FILTER_KEY) { uint32_t p = atomicAdd(&ctrl[0], 1u); if (p < cap) { keys[p] = k3; idxs[p] = 4u * i + 3u; } }
  }
  if (blockIdx.x == 0 && (int)threadIdx.x < ntail) {  // scalar tail (n % 4)
    int j = n4 * 4 + threadIdx.x;
    uint32_t kk = f2key(in_s[j]);
    atomicAdd(&lh[kk >> 20], 1u);
    if (kk >= FILTER_KEY) { uint32_t p = atomicAdd(&ctrl[0], 1u); if (p < cap) { keys[p] = kk; idxs[p] = (uint32_t)j; } }
  }
  __syncthreads();
  for (int i = threadIdx.x; i < HIST_BINS; i += blockDim.x) {
    uint32_t c = lh[i];
    if (c) atomicAdd(&ghist[i], c);
  }
}

// K2: bucket selection + filter validation
__global__ void k_select_bucket(const uint32_t* __restrict__ gh,
                                const int* __restrict__ kptr,
                                uint32_t* __restrict__ ctrl, uint32_t cap) {
  __shared__ uint32_t chunk[256];
  const int CPT = HIST_BINS / 256;  // 16 bins per thread
  int t = threadIdx.x;
  uint32_t s = 0;
  for (int i = 0; i < CPT; i++) s += gh[t * CPT + i];
  chunk[t] = s;
  __syncthreads();
  if (t == 0) {
    uint32_t K = (uint32_t)kptr[0];
    uint32_t above = 0;
    int sel = 0;
    for (int c = 255; c >= 0; c--) {
      if (above + chunk[c] >= K) { sel = c; break; }
      above += chunk[c];
    }
    int bsel = sel * CPT;
    for (int b = sel * CPT + CPT - 1; b >= sel * CPT; b--) {
      uint32_t c = gh[b];
      if (above + c >= K) { bsel = b; break; }
      above += c;
    }
    ctrl[1] = (uint32_t)bsel;
    ctrl[2] = K - above;  // 1-based rank within bucket (from the top)
    // filter valid <=> every possible winner key >= FILTER_KEY, i.e. the
    // selected bucket's base >= FILTER_KEY (low 20 bits of FILTER_KEY are 0)
    uint32_t nc = ctrl[0];
    bool valid = ((uint32_t)bsel >= (FILTER_KEY >> 20)) && (nc <= cap);
    if (!valid) { ctrl[0] = 0; ctrl[6] = 1; }  // discard list, flag fallback
    else ctrl[6] = 0;
  }
}

// K3: fallback gather (only when optimistic filter was insufficient):
// append every element whose bin >= selected bucket.
__global__ void __launch_bounds__(256) k_gather_fallback(
    const float4* __restrict__ in, int n4, int ntail,
    const float* __restrict__ in_s, uint32_t* __restrict__ ctrl,
    uint32_t* __restrict__ keys, uint32_t* __restrict__ idxs, uint32_t cap) {
  if (ctrl[6] == 0) return;  // common path: early-exit, ~dispatch cost only
  uint32_t sel = ctrl[1];
  int stride = gridDim.x * blockDim.x;
  for (int i = blockIdx.x * blockDim.x + threadIdx.x; i < n4; i += stride) {
    f32x4 v = *(const f32x4*)&in[i];
    uint32_t k0 = f2key(v.x), k1 = f2key(v.y), k2 = f2key(v.z), k3 = f2key(v.w);
    if ((k0 >> 20) >= sel) { uint32_t p = atomicAdd(&ctrl[0], 1u); if (p < cap) { keys[p] = k0; idxs[p] = 4u * i + 0u; } }
    if ((k1 >> 20) >= sel) { uint32_t p = atomicAdd(&ctrl[0], 1u); if (p < cap) { keys[p] = k1; idxs[p] = 4u * i + 1u; } }
    if ((k2 >> 20) >= sel) { uint32_t p = atomicAdd(&ctrl[0], 1u); if (p < cap) { keys[p] = k2; idxs[p] = 4u * i + 2u; } }
    if ((k3 >> 20) >= sel) { uint32_t p = atomicAdd(&ctrl[0], 1u); if (p < cap) { keys[p] = k3; idxs[p] = 4u * i + 3u; } }
  }
  if (blockIdx.x == 0 && (int)threadIdx.x < ntail) {
    int j = n4 * 4 + threadIdx.x;
    uint32_t kk = f2key(in_s[j]);
    if ((kk >> 20) >= sel) { uint32_t p = atomicAdd(&ctrl[0], 1u); if (p < cap) { keys[p] = kk; idxs[p] = (uint32_t)j; } }
  }
}

// K4: exact radix select over candidates (4 bits/round over remaining 20
// bits), then scatter-write ALL winners (key >= exact threshold) into the
// pre-zeroed output. Bit-exact key2f(f2key(x)) roundtrip.
__global__ void __launch_bounds__(1024) k_final(uint32_t* __restrict__ ctrl,
                                                const uint32_t* __restrict__ keys,
                                                const uint32_t* __restrict__ idxs,
                                                uint32_t cap,
                                                float* __restrict__ out_s) {
  __shared__ uint32_t sh[16384];
  __shared__ uint32_t cnt[16];
  __shared__ uint32_t s_p, s_want;
  int t = threadIdx.x;
  uint32_t n = ctrl[0]; if (n > cap) n = cap;
  bool useLds = (n <= 16384);
  if (useLds) for (uint32_t i = t; i < n; i += blockDim.x) sh[i] = keys[i];
  if (t == 0) { s_p = ctrl[1] << 20; s_want = ctrl[2]; }
  __syncthreads();
  uint32_t p = s_p;
  for (int d = 4; d >= 0; d--) {
    if (t < 16) cnt[t] = 0;
    __syncthreads();
    int sh_hi = 4 * d + 4;            // bits above (and incl.) current digit's top
    uint32_t pref = p >> sh_hi;       // fixed prefix (bucket bits + chosen digits)
    for (uint32_t i = t; i < n; i += blockDim.x) {
      uint32_t kk = useLds ? sh[i] : keys[i];
      if ((kk >> sh_hi) == pref) atomicAdd(&cnt[(kk >> (4 * d)) & 15u], 1u);
    }
    __syncthreads();
    if (t == 0) {
      uint32_t want = s_want, acc = 0;
      uint32_t v = 0;
      for (int x = 15; x >= 0; x--) {
        if (acc + cnt[x] >= want) { v = (uint32_t)x; break; }
        acc += cnt[x];
      }
      s_p = p | (v << (4 * d));
      s_want = want - acc;
    }
    __syncthreads();
    p = s_p;
  }
  if (t == 0) ctrl[3] = __float_as_uint(key2f(p));
  // scatter-write winners: every candidate at or above the exact threshold
  for (uint32_t i = t; i < n; i += blockDim.x) {
    uint32_t kk = useLds ? sh[i] : keys[i];
    if (kk >= p) out_s[idxs[i]] = key2f(kk);
  }
}

extern "C" void kernel_launch(void* const* d_in, const int* in_sizes, int n_in,
                              void* d_out, int out_size, void* d_ws, size_t ws_size,
                              hipStream_t stream) {
  const float* in = (const float*)d_in[0];
  const int* kptr = (const int*)d_in[1];
  float* out = (float*)d_out;
  int n = in_sizes[0];
  int n4 = n >> 2;
  int ntail = n & 3;

  uint32_t* ws = (uint32_t*)d_ws;
  uint32_t* ghist = ws;
  uint32_t* ctrl = ws + CTRL_OFF;
  size_t ws_words = ws_size / 4;
  uint32_t cap = 0;
  if (ws_words > CAND_OFF + 2) cap = (uint32_t)((ws_words - CAND_OFF) / 2);
  uint32_t* keys = ws + CAND_OFF;
  uint32_t* idxs = keys + cap;

  // zero histogram + control block (ws is poisoned 0xAA before each launch)
  hipMemsetAsync(d_ws, 0, CAND_OFF * sizeof(uint32_t), stream);
  // zero the WHOLE output at fill rate; winners are scatter-written by K4.
  // This replaces the entire read+write "apply" pass (256 MB of traffic).
  hipMemsetAsync(d_out, 0, (size_t)out_size, stream);

  k_hist_filter<<<1024, 256, 0, stream>>>((const float4*)in, n4, ntail, in,
                                          ghist, ctrl, keys, idxs, cap);
  k_select_bucket<<<1, 256, 0, stream>>>(ghist, kptr, ctrl, cap);
  k_gather_fallback<<<2048, 256, 0, stream>>>((const float4*)in, n4, ntail, in,
                                              ctrl, keys, idxs, cap);
  k_final<<<1, 1024, 0, stream>>>(ctrl, keys, idxs, cap, out);
}

// Round 5
// 295.157 us; speedup vs baseline: 1.0347x; 1.0347x over previous
//
#include <hip/hip_runtime.h>
#include <stdint.h>

// ---------------------------------------------------------------------------
// kWTA: threshold = K-th largest of N fp32; out[i] = in[i] < thr ? 0 : in[i]
//
// Insight chain (measured across rounds):
//  - r2: in-kernel grid fusion w/ device fences = 3x slower (L2 wb/inv storms)
//  - r4: the 4096-bin LDS histogram is latency-bound on SAME-ADDRESS atomic
//        serialization (Gaussian keys hit few bins; 104us, 8% HBM, 2.7M
//        LDS-conflict cycles). So: drop the histogram entirely.
//
// Fast path (validated at runtime, exact):
//   K1: ONE streaming pass: cached read of in, nontemporal zero-store of out,
//       and append (key,idx) to list A for every key >= f2key(3.5)
//       (~7.8k of 33.5M for N(0,1); no LDS, no histogram)
//   K2: fallback gather-ALL into list B -- early-exits when nA >= K (the
//       K-th largest overall is then provably among list A)
//   K3: single-block 8x4-bit radix select over full 32-bit keys of the
//       candidate list -> exact threshold; scatter-write winners (key >= thr)
//       into the already-zeroed output. Bit-exact key2f(f2key(x)) roundtrip.
// Fallback path (nA < K or overflow; never for benchmark data): list B holds
// ALL N (key,idx) pairs (ws = 512 MiB suffices), same select logic, exact.
// ---------------------------------------------------------------------------

// f2key(3.5f) = 0xC0600000
#define FILTER_KEY 0xC0600000u

// ctrl word offsets (ws[0..15])
//  ctrl[0] = list-A counter, ctrl[3] = threshold bits (debug), ctrl[7] = list-B counter

typedef float f32x4 __attribute__((ext_vector_type(4)));

__device__ __forceinline__ uint32_t f2key(float x) {
  uint32_t u = __float_as_uint(x);
  return (u & 0x80000000u) ? ~u : (u | 0x80000000u);  // larger key <=> larger float
}
__device__ __forceinline__ float key2f(uint32_t k) {
  uint32_t u = (k & 0x80000000u) ? (k & 0x7fffffffu) : ~k;
  return __uint_as_float(u);
}

// K1: zero the output + gather filter-passing candidates, one streaming pass.
__global__ void __launch_bounds__(256) k_zero_filter(
    const float4* __restrict__ in, float4* __restrict__ out, int n4, int ntail,
    const float* __restrict__ in_s, float* __restrict__ out_s,
    uint32_t* __restrict__ ctrl, uint32_t* __restrict__ keysA,
    uint32_t* __restrict__ idxsA, uint32_t capA) {
  int stride = gridDim.x * blockDim.x;
  f32x4 z = {0.0f, 0.0f, 0.0f, 0.0f};
  for (int i = blockIdx.x * blockDim.x + threadIdx.x; i < n4; i += stride) {
    f32x4 v = *(const f32x4*)&in[i];  // cached: L3 keeps input warm across iters
    uint32_t k0 = f2key(v.x), k1 = f2key(v.y), k2 = f2key(v.z), k3 = f2key(v.w);
    __builtin_nontemporal_store(z, (f32x4*)&out[i]);  // dense zero stream
    // rare (~2e-4) appends; exec-mask branches cost ~nothing when no lane takes
    if (k0 >= FILTER_KEY) { uint32_t p = atomicAdd(&ctrl[0], 1u); if (p < capA) { keysA[p] = k0; idxsA[p] = 4u * (uint32_t)i + 0u; } }
    if (k1 >= FILTER_KEY) { uint32_t p = atomicAdd(&ctrl[0], 1u); if (p < capA) { keysA[p] = k1; idxsA[p] = 4u * (uint32_t)i + 1u; } }
    if (k2 >= FILTER_KEY) { uint32_t p = atomicAdd(&ctrl[0], 1u); if (p < capA) { keysA[p] = k2; idxsA[p] = 4u * (uint32_t)i + 2u; } }
    if (k3 >= FILTER_KEY) { uint32_t p = atomicAdd(&ctrl[0], 1u); if (p < capA) { keysA[p] = k3; idxsA[p] = 4u * (uint32_t)i + 3u; } }
  }
  if (blockIdx.x == 0 && (int)threadIdx.x < ntail) {  // scalar tail (n % 4)
    int j = n4 * 4 + threadIdx.x;
    uint32_t kk = f2key(in_s[j]);
    out_s[j] = 0.0f;
    if (kk >= FILTER_KEY) { uint32_t p = atomicAdd(&ctrl[0], 1u); if (p < capA) { keysA[p] = kk; idxsA[p] = (uint32_t)j; } }
  }
}

// K2: fallback — gather ALL (key,idx) into list B. Early-exits on the fast
// path (nA >= K and list A not overflowed). Never triggers for N(0,1) data;
// exists to keep the kernel exact for arbitrary inputs.
__global__ void __launch_bounds__(256) k_gather_all(
    const float4* __restrict__ in, int n4, int ntail,
    const float* __restrict__ in_s, const int* __restrict__ kptr,
    uint32_t* __restrict__ ctrl, uint32_t* __restrict__ keysB,
    uint32_t* __restrict__ idxsB, uint32_t capA, uint32_t capB) {
  uint32_t K = (uint32_t)kptr[0];
  uint32_t nA = ctrl[0];
  if (nA >= K && nA <= capA) return;  // fast path: dispatch-cost only
  int stride = gridDim.x * blockDim.x;
  for (int i = blockIdx.x * blockDim.x + threadIdx.x; i < n4; i += stride) {
    f32x4 v = *(const f32x4*)&in[i];
    uint32_t kk[4] = {f2key(v.x), f2key(v.y), f2key(v.z), f2key(v.w)};
    uint32_t p = atomicAdd(&ctrl[7], 4u);
    for (int c = 0; c < 4; c++)
      if (p + c < capB) { keysB[p + c] = kk[c]; idxsB[p + c] = 4u * (uint32_t)i + c; }
  }
  if (blockIdx.x == 0 && (int)threadIdx.x < ntail) {
    int j = n4 * 4 + threadIdx.x;
    uint32_t p = atomicAdd(&ctrl[7], 1u);
    if (p < capB) { keysB[p] = f2key(in_s[j]); idxsB[p] = (uint32_t)j; }
  }
}

// K3: exact radix select over the full 32-bit keys (8 rounds x 4 bits) of
// the candidate list, then scatter-write winners into the zeroed output.
__global__ void __launch_bounds__(1024) k_final(
    const int* __restrict__ kptr, uint32_t* __restrict__ ctrl,
    const uint32_t* __restrict__ keysA, const uint32_t* __restrict__ idxsA,
    uint32_t capA, const uint32_t* __restrict__ keysB,
    const uint32_t* __restrict__ idxsB, uint32_t capB,
    float* __restrict__ out_s) {
  __shared__ uint32_t sh[16384];
  __shared__ uint32_t cnt[16];
  __shared__ uint32_t s_p, s_want;
  int t = threadIdx.x;
  uint32_t K = (uint32_t)kptr[0];
  uint32_t nA = ctrl[0];
  bool useA = (nA >= K && nA <= capA);
  const uint32_t* keys = useA ? keysA : keysB;
  const uint32_t* idxs = useA ? idxsA : idxsB;
  uint32_t n = useA ? nA : ctrl[7];
  if (!useA && n > capB) n = capB;
  bool useLds = (n <= 16384);
  if (useLds) for (uint32_t i = t; i < n; i += blockDim.x) sh[i] = keys[i];
  if (t == 0) { s_p = 0u; s_want = K; }
  __syncthreads();
  uint32_t p = s_p;
  for (int d = 7; d >= 0; d--) {
    if (t < 16) cnt[t] = 0;
    __syncthreads();
    int sh_hi = 4 * d + 4;  // bits above current digit (32 on first round)
    uint32_t pref = (sh_hi < 32) ? (p >> sh_hi) : 0u;
    for (uint32_t i = t; i < n; i += blockDim.x) {
      uint32_t kk = useLds ? sh[i] : keys[i];
      uint32_t hi = (sh_hi < 32) ? (kk >> sh_hi) : 0u;
      if (hi == pref) atomicAdd(&cnt[(kk >> (4 * d)) & 15u], 1u);
    }
    __syncthreads();
    if (t == 0) {
      uint32_t want = s_want, acc = 0, v = 0;
      for (int x = 15; x >= 0; x--) {
        if (acc + cnt[x] >= want) { v = (uint32_t)x; break; }
        acc += cnt[x];
      }
      s_p = p | (v << (4 * d));
      s_want = want - acc;
    }
    __syncthreads();
    p = s_p;
  }
  if (t == 0) ctrl[3] = __float_as_uint(key2f(p));
  // scatter winners: candidates at or above the exact K-th-largest key
  // (ties at the threshold value are all kept, matching where(in<thr,0,in))
  for (uint32_t i = t; i < n; i += blockDim.x) {
    uint32_t kk = useLds ? sh[i] : keys[i];
    if (kk >= p) out_s[idxs[i]] = key2f(kk);
  }
}

extern "C" void kernel_launch(void* const* d_in, const int* in_sizes, int n_in,
                              void* d_out, int out_size, void* d_ws, size_t ws_size,
                              hipStream_t stream) {
  const float* in = (const float*)d_in[0];
  const int* kptr = (const int*)d_in[1];
  float* out = (float*)d_out;
  int n = in_sizes[0];
  int n4 = n >> 2;
  int ntail = n & 3;

  uint32_t* ws = (uint32_t*)d_ws;
  uint32_t* ctrl = ws;  // 16 words
  size_t ws_words = ws_size / 4;
  size_t avail = (ws_words > 16) ? (ws_words - 16) : 0;
  uint32_t capA = (uint32_t)((avail / 4 < (1u << 20)) ? avail / 4 : (1u << 20));
  uint32_t* keysA = ws + 16;
  uint32_t* idxsA = keysA + capA;
  size_t availB = avail - 2 * (size_t)capA;
  uint32_t capB = (uint32_t)(availB / 2);  // >= N with the 512 MiB workspace
  uint32_t* keysB = idxsA + capA;
  uint32_t* idxsB = keysB + capB;

  // zero only the 64-byte control block (ws is poisoned before each launch)
  hipMemsetAsync(d_ws, 0, 16 * sizeof(uint32_t), stream);

  k_zero_filter<<<2048, 256, 0, stream>>>((const float4*)in, (float4*)out,
                                          n4, ntail, in, out, ctrl,
                                          keysA, idxsA, capA);
  k_gather_all<<<2048, 256, 0, stream>>>((const float4*)in, n4, ntail, in,
                                         kptr, ctrl, keysB, idxsB, capA, capB);
  k_final<<<1, 1024, 0, stream>>>(kptr, ctrl, keysA, idxsA, capA,
                                  keysB, idxsB, capB, out);
}